// Round 4
// baseline (203.523 us; speedup 1.0000x reference)
//
#include <hip/hip_runtime.h>

// PPO loss, T = 2^23 fp32.
// out = -sum(min(ratio*adv, clip(ratio)*adv)) + C1*sum((v-ret)^2) - C2*sum(p*log(p+1e-5))
// adv: reverse scan gae = (gl)*gae + delta ; ret: reverse scan acc = g*acc + r.
// Constant-coefficient reverse scans => per-chunk exact-to-fp32 with geometric halo
// (W=1024; absmax was 0.0 at this window in rounds 2-3).
//
// Round 4: persistent blocks (grid=256, 1/CU), K=4 chunks of 8192 per block,
// software-pipelined: next chunk's r/v/halo prefetched into the alternate register
// set BEFORE the current chunk's barrier; raw s_barrier + manual lgkmcnt(0) only
// (no vmcnt drain -> prefetch stays in flight across the barrier). Double-buffered
// 32-float LDS exchange, one barrier per iteration.

#define T_TOTAL  8388608L
#define CHUNK    8192
#define NCHUNK   1024
#define GRID     256
#define K_ITERS  4
#define NT       512                   // 8 waves
#define NW       8

#define EPSF 0.2f
#define GF   0.99f
#define C1F  0.5f
#define C2F  0.01f
#define AGLF ((float)(0.99 * 0.95))

constexpr float fpowc(double a, int n) {
    double r = 1.0;
    for (int i = 0; i < n; ++i) r *= a;
    return (float)r;
}
constexpr float AG2    = fpowc(0.99 * 0.95, 2);
constexpr float AG4    = fpowc(0.99 * 0.95, 4);
constexpr float AG8    = fpowc(0.99 * 0.95, 8);
constexpr float AG16   = fpowc(0.99 * 0.95, 16);
constexpr float AG32   = fpowc(0.99 * 0.95, 32);
constexpr float AG64   = fpowc(0.99 * 0.95, 64);
constexpr float AG128  = fpowc(0.99 * 0.95, 128);
constexpr float AG256  = fpowc(0.99 * 0.95, 256);
constexpr float AG512  = fpowc(0.99 * 0.95, 512);
constexpr float AG1024 = fpowc(0.99 * 0.95, 1024);
constexpr float G2    = fpowc(0.99, 2);
constexpr float G4    = fpowc(0.99, 4);
constexpr float G8    = fpowc(0.99, 8);
constexpr float G16   = fpowc(0.99, 16);
constexpr float G32   = fpowc(0.99, 32);
constexpr float G64   = fpowc(0.99, 64);
constexpr float G128  = fpowc(0.99, 128);
constexpr float G256  = fpowc(0.99, 256);
constexpr float G512  = fpowc(0.99, 512);
constexpr float G1024 = fpowc(0.99, 1024);

// element i (compile-time const under #pragma unroll) of a float4[4] register block
__device__ __forceinline__ float g4(const float4* a, int i) {
    const float4 f = a[i >> 2];
    return (i & 3) == 0 ? f.x : (i & 3) == 1 ? f.y : (i & 3) == 2 ? f.z : f.w;
}

// inclusive wave suffix scan with geometric lane-step weight w0 (6 shfls, no barriers)
__device__ __forceinline__ float wscan(float val, float w, int lane) {
#pragma unroll
    for (int s = 1; s < 64; s <<= 1) {
        float o = __shfl_down(val, s, 64);
        val += (lane + s < 64) ? w * o : 0.0f;
        w *= w;
    }
    return val;
}

struct SetRV {                       // per-chunk r/v + halo state (double-buffered A/B)
    float4 r4[4], v4[4];
    float hr0, hr1, hv0, hv1, hva, vlast;
};
struct Inv { int lane, wid; float wgl, wrl, hwg, hwr; };

__device__ __forceinline__ void load_rv(SetRV& s, const float* __restrict__ R,
                                        const float* __restrict__ V,
                                        long base, int j, bool halo)
{
    const long g0 = base + 16L * j;
#pragma unroll
    for (int b = 0; b < 4; ++b) {
        s.r4[b] = *reinterpret_cast<const float4*>(R + g0 + 4 * b);
        s.v4[b] = *reinterpret_cast<const float4*>(V + g0 + 4 * b);
    }
    s.vlast = (g0 + 16 < T_TOTAL) ? V[g0 + 16] : 0.0f;
    if (halo) {
        const long hb = base + CHUNK + 2L * j;
        const float2 hr = *reinterpret_cast<const float2*>(R + hb);
        const float2 hv = *reinterpret_cast<const float2*>(V + hb);
        s.hr0 = hr.x; s.hr1 = hr.y; s.hv0 = hv.x; s.hv1 = hv.y;
        s.hva = V[hb + 2];
    } else {
        s.hr0 = s.hr1 = s.hv0 = s.hv1 = s.hva = 0.0f;
    }
}

// scan + barrier + carry + fused loss for one chunk; pq loaded by caller (issued early)
__device__ __forceinline__ float process(const SetRV& s, const float4* p4, const float4* q4,
                                         const Inv& iv, float* b)
{
    // delta + per-thread Horner partials over own 16 contiguous elems
    float d[16];
#pragma unroll
    for (int i = 0; i < 16; ++i) {
        const float vn = (i < 15) ? g4(s.v4, i + 1) : s.vlast;
        d[i] = g4(s.r4, i) - g4(s.v4, i) + GF * vn;
    }
    float Pg = 0.0f, Pr = 0.0f;
#pragma unroll
    for (int i = 15; i >= 0; --i) {
        Pg = fmaf(AGLF, Pg, d[i]);
        Pr = fmaf(GF,   Pr, g4(s.r4, i));
    }
    const float Ug = wscan(Pg, AG16, iv.lane);
    const float Ur = wscan(Pr, G16,  iv.lane);
    float sng = __shfl_down(Ug, 1, 64); sng = (iv.lane < 63) ? sng : 0.0f;
    float snr = __shfl_down(Ur, 1, 64); snr = (iv.lane < 63) ? snr : 0.0f;

    // halo partial: thread covers halo elems [2j, 2j+2); weighted butterfly sum per wave
    float hg, hr;
    {
        const float d0 = s.hr0 - s.hv0 + GF * s.hv1;
        const float d1 = s.hr1 - s.hv1 + GF * s.hva;
        hg = (d0 + AGLF * d1) * iv.hwg;          // pre-weight a^(2*lane)
        hr = (s.hr0 + GF * s.hr1) * iv.hwr;
    }
#pragma unroll
    for (int t = 1; t < 64; t <<= 1) {
        hg += __shfl_xor(hg, t, 64);
        hr += __shfl_xor(hr, t, 64);
    }
    if (iv.lane == 0) {
        b[iv.wid]      = hg;   // wave halo-strip partial (128 elems)
        b[8 + iv.wid]  = hr;
        b[16 + iv.wid] = Ug;   // wave total (1024 elems)
        b[24 + iv.wid] = Ur;
    }
    __builtin_amdgcn_sched_barrier(0);
    asm volatile("s_waitcnt lgkmcnt(0)" ::: "memory");   // LDS writes visible; vmcnt untouched
    __builtin_amdgcn_s_barrier();                        // raw barrier: prefetch stays in flight
    __builtin_amdgcn_sched_barrier(0);

    const float4 Hg0 = *reinterpret_cast<const float4*>(&b[0]);
    const float4 Hg1 = *reinterpret_cast<const float4*>(&b[4]);
    const float4 Hr0 = *reinterpret_cast<const float4*>(&b[8]);
    const float4 Hr1 = *reinterpret_cast<const float4*>(&b[12]);
    const float4 Wg0 = *reinterpret_cast<const float4*>(&b[16]);
    const float4 Wg1 = *reinterpret_cast<const float4*>(&b[20]);
    const float4 Wr0 = *reinterpret_cast<const float4*>(&b[24]);
    const float4 Wr1 = *reinterpret_cast<const float4*>(&b[28]);
    const float Hg[8] = {Hg0.x,Hg0.y,Hg0.z,Hg0.w,Hg1.x,Hg1.y,Hg1.z,Hg1.w};
    const float Hr[8] = {Hr0.x,Hr0.y,Hr0.z,Hr0.w,Hr1.x,Hr1.y,Hr1.z,Hr1.w};
    const float Wg[8] = {Wg0.x,Wg0.y,Wg0.z,Wg0.w,Wg1.x,Wg1.y,Wg1.z,Wg1.w};
    const float Wr[8] = {Wr0.x,Wr0.y,Wr0.z,Wr0.w,Wr1.x,Wr1.y,Wr1.z,Wr1.w};

    // halo carry at chunk end: K = sum_w a^(128w) * H_w
    float Kg = 0.0f, Kr = 0.0f;
#pragma unroll
    for (int w = 7; w >= 0; --w) { Kg = fmaf(AG128, Kg, Hg[w]); Kr = fmaf(G128, Kr, Hr[w]); }
    // carry entering this wave's 1024-elem region (all indices compile-time: rule #20)
    float Cg = Kg, Cr = Kr;
#pragma unroll
    for (int w = 7; w >= 1; --w) {
        if (w > iv.wid) { Cg = fmaf(AG1024, Cg, Wg[w]); Cr = fmaf(G1024, Cr, Wr[w]); }
    }
    float y  = fmaf(iv.wgl, Cg, sng);   // scan value entering this lane's 16-run
    float tt = fmaf(iv.wrl, Cr, snr);

    // fused reverse scan + loss
    float acc = 0.0f;
#pragma unroll
    for (int i = 15; i >= 0; --i) {
        y  = fmaf(AGLF, y, d[i]);            // advantage at elem i
        tt = fmaf(GF, tt, g4(s.r4, i));      // value target at elem i
        const float pi = g4(p4, i), qi = g4(q4, i);
        const float rt   = __fdividef(pi, qi);
        const float cl   = fminf(fmaxf(rt, 1.0f - EPSF), 1.0f + EPSF);
        const float term = fminf(rt * y, cl * y);
        const float vd   = g4(s.v4, i) - tt;
        acc = fmaf(C1F * vd, vd, acc) - term - C2F * pi * __logf(pi + 1e-5f);
    }
    return acc;
}

__global__ __launch_bounds__(NT) void ppo_main(
    const float* __restrict__ probs,
    const float* __restrict__ probs_old,
    const float* __restrict__ rewards,
    const float* __restrict__ values,
    float* __restrict__ out)
{
    __shared__ float sb[2][32];
    __shared__ float sRed[NW];

    const int j = threadIdx.x, lane = j & 63, wid = j >> 6;
    Inv iv; iv.lane = lane; iv.wid = wid;
    {   // main-scan lane carry weight a^(16*(63-lane)); halo pre-weight a^(2*lane)
        const int k63 = 63 - lane;
        float wg = 1.f, wr = 1.f;
        if (k63 & 1)  { wg *= AG16;  wr *= G16;  }
        if (k63 & 2)  { wg *= AG32;  wr *= G32;  }
        if (k63 & 4)  { wg *= AG64;  wr *= G64;  }
        if (k63 & 8)  { wg *= AG128; wr *= G128; }
        if (k63 & 16) { wg *= AG256; wr *= G256; }
        if (k63 & 32) { wg *= AG512; wr *= G512; }
        iv.wgl = wg; iv.wrl = wr;
        float hg = 1.f, hr = 1.f;
        if (lane & 1)  { hg *= AG2;  hr *= G2;  }
        if (lane & 2)  { hg *= AG4;  hr *= G4;  }
        if (lane & 4)  { hg *= AG8;  hr *= G8;  }
        if (lane & 8)  { hg *= AG16; hr *= G16; }
        if (lane & 16) { hg *= AG32; hr *= G32; }
        if (lane & 32) { hg *= AG64; hr *= G64; }
        iv.hwg = hg; iv.hwr = hr;
    }

    const long base0 = (long)blockIdx.x * (K_ITERS * (long)CHUNK);  // 4 consecutive chunks
    const long g16   = 16L * j;
    const bool lastBlk = (blockIdx.x == GRID - 1);

    SetRV A, B;
    float4 p4[4], q4[4];
    float acc = 0.0f;

    // prologue: chunk c0 r/v + its p/q
    load_rv(A, rewards, values, base0, j, true);
#pragma unroll
    for (int bq = 0; bq < 4; ++bq) {
        p4[bq] = *reinterpret_cast<const float4*>(probs     + base0 + g16 + 4 * bq);
        q4[bq] = *reinterpret_cast<const float4*>(probs_old + base0 + g16 + 4 * bq);
    }

    // iter 0: prefetch c1 r/v, process c0
    load_rv(B, rewards, values, base0 + CHUNK, j, true);
    acc += process(A, p4, q4, iv, sb[0]);

    // iter 1: p/q(c1) first, prefetch c2 r/v, process c1
#pragma unroll
    for (int bq = 0; bq < 4; ++bq) {
        p4[bq] = *reinterpret_cast<const float4*>(probs     + base0 + CHUNK + g16 + 4 * bq);
        q4[bq] = *reinterpret_cast<const float4*>(probs_old + base0 + CHUNK + g16 + 4 * bq);
    }
    load_rv(A, rewards, values, base0 + 2L * CHUNK, j, true);
    acc += process(B, p4, q4, iv, sb[1]);

    // iter 2: p/q(c2) first, prefetch c3 r/v (halo off for the global last chunk), process c2
#pragma unroll
    for (int bq = 0; bq < 4; ++bq) {
        p4[bq] = *reinterpret_cast<const float4*>(probs     + base0 + 2L * CHUNK + g16 + 4 * bq);
        q4[bq] = *reinterpret_cast<const float4*>(probs_old + base0 + 2L * CHUNK + g16 + 4 * bq);
    }
    load_rv(B, rewards, values, base0 + 3L * CHUNK, j, !lastBlk);
    acc += process(A, p4, q4, iv, sb[0]);

    // iter 3: p/q(c3), process c3
#pragma unroll
    for (int bq = 0; bq < 4; ++bq) {
        p4[bq] = *reinterpret_cast<const float4*>(probs     + base0 + 3L * CHUNK + g16 + 4 * bq);
        q4[bq] = *reinterpret_cast<const float4*>(probs_old + base0 + 3L * CHUNK + g16 + 4 * bq);
    }
    acc += process(B, p4, q4, iv, sb[1]);

    // final reduction: wave butterfly -> 8 partials -> one atomic per block
#pragma unroll
    for (int t = 32; t >= 1; t >>= 1) acc += __shfl_down(acc, t, 64);
    if (lane == 0) sRed[wid] = acc;
    __syncthreads();   // nothing outstanding; implicit drain is free here
    if (j == 0) {
        float tot = 0.0f;
#pragma unroll
        for (int w = 0; w < NW; ++w) tot += sRed[w];
        atomicAdd(out, tot);
    }
}

extern "C" void kernel_launch(void* const* d_in, const int* in_sizes, int n_in,
                              void* d_out, int out_size, void* d_ws, size_t ws_size,
                              hipStream_t stream) {
    const float* probs     = (const float*)d_in[0];
    const float* probs_old = (const float*)d_in[1];
    const float* rewards   = (const float*)d_in[2];
    const float* values    = (const float*)d_in[3];
    float* out = (float*)d_out;

    hipMemsetAsync(out, 0, sizeof(float), stream);   // d_out is poisoned 0xAA before every call
    ppo_main<<<GRID, NT, 0, stream>>>(probs, probs_old, rewards, values, out);
}

// Round 5
// 173.328 us; speedup vs baseline: 1.1742x; 1.1742x over previous
//
#include <hip/hip_runtime.h>

// PPO loss, T = 2^23 fp32.
// out = -sum(min(ratio*adv, clip(ratio)*adv)) + C1*sum((v-ret)^2) - C2*sum(p*log(p+1e-5))
// adv: reverse scan gae = (gl)*gae + delta ; ret: reverse scan acc = g*acc + r.
// Constant-coefficient reverse scans => per-chunk exact-to-fp32 via geometric halo
// (W=1024; absmax 0.0 in rounds 1-4 at this window).
//
// Round 5: small blocks + 3x oversubscription for scheduler-staggered load issue.
// 4096 blocks x 256 threads, chunk=2048 (8 elems/thread), halo=1024 (4/thread).
// Per-wave shfl scans (no barriers), ONE raw s_barrier + lgkmcnt(0) (no vmcnt drain),
// pre-barrier div/log overlap. No register double-buffering (round-4 spill lesson).

#define T_TOTAL 8388608L
#define CHUNK   2048
#define NBLK    4096
#define NT      256
#define NW      4

#define EPSF 0.2f
#define GF   0.99f
#define C1F  0.5f
#define C2F  0.01f
#define AGLF ((float)(0.99 * 0.95))

constexpr float fpowc(double a, int n) {
    double r = 1.0;
    for (int i = 0; i < n; ++i) r *= a;
    return (float)r;
}
constexpr float AG4   = fpowc(0.99 * 0.95, 4);
constexpr float AG8   = fpowc(0.99 * 0.95, 8);
constexpr float AG16  = fpowc(0.99 * 0.95, 16);
constexpr float AG32  = fpowc(0.99 * 0.95, 32);
constexpr float AG64  = fpowc(0.99 * 0.95, 64);
constexpr float AG128 = fpowc(0.99 * 0.95, 128);
constexpr float AG256 = fpowc(0.99 * 0.95, 256);
constexpr float AG512 = fpowc(0.99 * 0.95, 512);
constexpr float G4    = fpowc(0.99, 4);
constexpr float G8    = fpowc(0.99, 8);
constexpr float G16   = fpowc(0.99, 16);
constexpr float G32   = fpowc(0.99, 32);
constexpr float G64   = fpowc(0.99, 64);
constexpr float G128  = fpowc(0.99, 128);
constexpr float G256  = fpowc(0.99, 256);
constexpr float G512  = fpowc(0.99, 512);

// inclusive wave suffix scan, geometric lane-step weight w0 (6 shfls, no barriers)
__device__ __forceinline__ float wscan(float val, float w, int lane) {
#pragma unroll
    for (int s = 1; s < 64; s <<= 1) {
        float o = __shfl_down(val, s, 64);
        val += (lane + s < 64) ? w * o : 0.0f;
        w *= w;
    }
    return val;
}

// element i (compile-time under #pragma unroll) of a float4 pair
__device__ __forceinline__ float g8(const float4& a, const float4& b, int i) {
    const float4 f = (i < 4) ? a : b;
    const int k = i & 3;
    return k == 0 ? f.x : k == 1 ? f.y : k == 2 ? f.z : f.w;
}

__global__ __launch_bounds__(NT) void ppo_main(
    const float* __restrict__ probs,
    const float* __restrict__ probs_old,
    const float* __restrict__ rewards,
    const float* __restrict__ values,
    float* __restrict__ out)
{
    __shared__ float sx[16];      // {Hg[4], Hr[4], Wg[4], Wr[4]}
    __shared__ float sRed[NW];

    const int  j    = threadIdx.x;
    const int  lane = j & 63;
    const int  wid  = j >> 6;
    const int  c    = blockIdx.x;
    const long base = (long)c * CHUNK;
    const long g0   = base + 8L * j;
    const bool has_halo = (c != NBLK - 1);

    // ---------------- loads: r/v + halo first, p/q last ----------------
    const float4 r40 = *reinterpret_cast<const float4*>(rewards + g0);
    const float4 r41 = *reinterpret_cast<const float4*>(rewards + g0 + 4);
    const float4 v40 = *reinterpret_cast<const float4*>(values  + g0);
    const float4 v41 = *reinterpret_cast<const float4*>(values  + g0 + 4);
    // wave-end v (uniform per wave): v[base + 512*(wid+1)]
    const long we = base + 512L * (wid + 1);
    const float vwend = (we < T_TOTAL) ? values[we] : 0.0f;

    float4 hr4 = make_float4(0,0,0,0), hv4 = make_float4(0,0,0,0);
    float  hvn = 0.0f;
    if (has_halo) {
        const long hb = base + CHUNK + 4L * j;
        hr4 = *reinterpret_cast<const float4*>(rewards + hb);
        hv4 = *reinterpret_cast<const float4*>(values  + hb);
        hvn = values[base + CHUNK + 256L * wid + 256];   // uniform per wave, in range
    }
    const float4 p40 = *reinterpret_cast<const float4*>(probs     + g0);
    const float4 p41 = *reinterpret_cast<const float4*>(probs     + g0 + 4);
    const float4 q40 = *reinterpret_cast<const float4*>(probs_old + g0);
    const float4 q41 = *reinterpret_cast<const float4*>(probs_old + g0 + 4);

    // ---------------- main: delta + Horner over 8 elems, wave scan ----------------
    float vn7;   // v[g0+8] = neighbor lane's v40.x; lane 63 -> wave-end scalar
    {
        float t = __shfl_down(v40.x, 1, 64);
        vn7 = (lane < 63) ? t : vwend;
    }
    float d[8];
#pragma unroll
    for (int i = 0; i < 7; ++i) d[i] = g8(r40, r41, i) - g8(v40, v41, i) + GF * g8(v40, v41, i + 1);
    d[7] = r41.w - v41.w + GF * vn7;

    float Pg = 0.0f, Pr = 0.0f;
#pragma unroll
    for (int i = 7; i >= 0; --i) {
        Pg = fmaf(AGLF, Pg, d[i]);
        Pr = fmaf(GF,   Pr, g8(r40, r41, i));
    }
    const float Ug = wscan(Pg, AG8, lane);
    const float Ur = wscan(Pr, G8,  lane);
    float sng = __shfl_down(Ug, 1, 64); sng = (lane < 63) ? sng : 0.0f;
    float snr = __shfl_down(Ur, 1, 64); snr = (lane < 63) ? snr : 0.0f;

    // ---------------- halo: per-thread 4-elem Horner, pre-weighted butterfly ----------------
    float hg = 0.0f, hr = 0.0f;
    {
        float t = __shfl_down(hv4.x, 1, 64);
        const float vn3 = (lane < 63) ? t : hvn;
        const float d0 = hr4.x - hv4.x + GF * hv4.y;
        const float d1 = hr4.y - hv4.y + GF * hv4.z;
        const float d2 = hr4.z - hv4.z + GF * hv4.w;
        const float d3 = hr4.w - hv4.w + GF * vn3;
        // pre-weight a^(4*lane)
        float pwg = 1.f, pwr = 1.f;
        if (lane & 1)  { pwg *= AG4;   pwr *= G4;   }
        if (lane & 2)  { pwg *= AG8;   pwr *= G8;   }
        if (lane & 4)  { pwg *= AG16;  pwr *= G16;  }
        if (lane & 8)  { pwg *= AG32;  pwr *= G32;  }
        if (lane & 16) { pwg *= AG64;  pwr *= G64;  }
        if (lane & 32) { pwg *= AG128; pwr *= G128; }
        hg = (d0 + AGLF * (d1 + AGLF * (d2 + AGLF * d3))) * pwg;
        hr = (hr4.x + GF * (hr4.y + GF * (hr4.z + GF * hr4.w))) * pwr;
#pragma unroll
        for (int t2 = 1; t2 < 64; t2 <<= 1) {
            hg += __shfl_xor(hg, t2, 64);
            hr += __shfl_xor(hr, t2, 64);
        }
    }
    if (lane == 0) {
        sx[wid]      = hg;   // halo strip partial (256 elems)
        sx[4 + wid]  = hr;
        sx[8 + wid]  = Ug;   // wave main total (512 elems)
        sx[12 + wid] = Ur;
    }

    // ---------------- pre-barrier heavy VALU: ratio + entropy (overlaps p/q latency) ------
    float rt[8];
    float acc = 0.0f;   // entropy part accumulates here
#pragma unroll
    for (int i = 0; i < 8; ++i) {
        const float pi = g8(p40, p41, i);
        rt[i] = __fdividef(pi, g8(q40, q41, i));
        acc -= C2F * pi * __logf(pi + 1e-5f);
    }

    __builtin_amdgcn_sched_barrier(0);
    asm volatile("s_waitcnt lgkmcnt(0)" ::: "memory");   // LDS writes visible; vmcnt untouched
    __builtin_amdgcn_s_barrier();
    __builtin_amdgcn_sched_barrier(0);

    // ---------------- carries ----------------
    const float4 Hgv = *reinterpret_cast<const float4*>(&sx[0]);
    const float4 Hrv = *reinterpret_cast<const float4*>(&sx[4]);
    const float4 Wgv = *reinterpret_cast<const float4*>(&sx[8]);
    const float4 Wrv = *reinterpret_cast<const float4*>(&sx[12]);

    // halo carry at chunk end: K = H0 + a^256 (H1 + a^256 (H2 + a^256 H3))
    float Kg = Hgv.x + AG256 * (Hgv.y + AG256 * (Hgv.z + AG256 * Hgv.w));
    float Kr = Hrv.x + G256  * (Hrv.y + G256  * (Hrv.z + G256  * Hrv.w));
    // carry entering this wave's 512-elem region (compile-time indices, wid-uniform preds)
    float Cg = Kg, Cr = Kr;
    if (3 > wid) { Cg = fmaf(AG512, Cg, Wgv.w); Cr = fmaf(G512, Cr, Wrv.w); }
    if (2 > wid) { Cg = fmaf(AG512, Cg, Wgv.z); Cr = fmaf(G512, Cr, Wrv.z); }
    if (1 > wid) { Cg = fmaf(AG512, Cg, Wgv.y); Cr = fmaf(G512, Cr, Wrv.y); }

    // per-lane carry weight a^(8*(63-lane))
    const int k63 = 63 - lane;
    float wgl = 1.f, wrl = 1.f;
    if (k63 & 1)  { wgl *= AG8;   wrl *= G8;   }
    if (k63 & 2)  { wgl *= AG16;  wrl *= G16;  }
    if (k63 & 4)  { wgl *= AG32;  wrl *= G32;  }
    if (k63 & 8)  { wgl *= AG64;  wrl *= G64;  }
    if (k63 & 16) { wgl *= AG128; wrl *= G128; }
    if (k63 & 32) { wgl *= AG256; wrl *= G256; }

    float y  = fmaf(wgl, Cg, sng);   // advantage-scan value entering this lane's 8-run
    float tt = fmaf(wrl, Cr, snr);   // return-scan value entering this lane's 8-run

    // ---------------- fused reverse scan + loss over own 8 elems ----------------
#pragma unroll
    for (int i = 7; i >= 0; --i) {
        y  = fmaf(AGLF, y, d[i]);             // advantage at elem i
        tt = fmaf(GF, tt, g8(r40, r41, i));   // value target at elem i
        const float rti  = rt[i];
        const float cl   = fminf(fmaxf(rti, 1.0f - EPSF), 1.0f + EPSF);
        const float term = fminf(rti * y, cl * y);
        const float vd   = g8(v40, v41, i) - tt;
        acc = fmaf(C1F * vd, vd, acc) - term;
    }

    // ---------------- reduce: wave butterfly -> 4 partials -> one atomic ----------------
#pragma unroll
    for (int t = 32; t >= 1; t >>= 1) acc += __shfl_down(acc, t, 64);
    if (lane == 0) sRed[wid] = acc;
    __syncthreads();
    if (j == 0) atomicAdd(out, (sRed[0] + sRed[1]) + (sRed[2] + sRed[3]));
}

extern "C" void kernel_launch(void* const* d_in, const int* in_sizes, int n_in,
                              void* d_out, int out_size, void* d_ws, size_t ws_size,
                              hipStream_t stream) {
    const float* probs     = (const float*)d_in[0];
    const float* probs_old = (const float*)d_in[1];
    const float* rewards   = (const float*)d_in[2];
    const float* values    = (const float*)d_in[3];
    float* out = (float*)d_out;

    hipMemsetAsync(out, 0, sizeof(float), stream);   // d_out is poisoned 0xAA before every call
    ppo_main<<<NBLK, NT, 0, stream>>>(probs, probs_old, rewards, values, out);
}

// Round 6
// 158.937 us; speedup vs baseline: 1.2805x; 1.0905x over previous
//
#include <hip/hip_runtime.h>

// PPO loss, T = 2^23 fp32.
// out = -sum(min(ratio*adv, clip(ratio)*adv)) + C1*sum((v-ret)^2) - C2*sum(p*log(p+1e-5))
// adv: reverse scan gae = (gl)*gae + delta ; ret: reverse scan acc = g*acc + r.
// Constant-coefficient reverse scans => per-chunk exact-to-fp32 via geometric halo
// (W=1024; absmax 0.0 in rounds 1-5 at this window).
//
// Round 6: amortize per-wave fixed cost (scan/halo/reduce crosslane ops ~40 DS/wave,
// measured ~14.5ns each serialized) over 2x elements: 32 elems/thread, chunk 8192
// @ NT=256, 1024 blocks (4/CU resident at <=128 VGPR). p/q loaded POST-barrier via
// static ping-pong prefetch (distance 2) so r/v and p/q register sets don't fully
// coexist (round-4 spill lesson). One raw s_barrier + lgkmcnt(0) only.

#define T_TOTAL 8388608L
#define CHUNK   8192
#define NBLK    1024
#define NT      256
#define NW      4
#define MPT     32                    // elems per thread

#define EPSF 0.2f
#define GF   0.99f
#define C1F  0.5f
#define C2F  0.01f
#define AGLF ((float)(0.99 * 0.95))

constexpr float fpowc(double a, int n) {
    double r = 1.0;
    for (int i = 0; i < n; ++i) r *= a;
    return (r < 1e-40) ? 0.0f : (float)r;   // clamp underflow (a^2048 ~ 3e-55)
}
constexpr float AG4    = fpowc(0.99 * 0.95, 4);
constexpr float AG8    = fpowc(0.99 * 0.95, 8);
constexpr float AG16   = fpowc(0.99 * 0.95, 16);
constexpr float AG32   = fpowc(0.99 * 0.95, 32);
constexpr float AG64   = fpowc(0.99 * 0.95, 64);
constexpr float AG128  = fpowc(0.99 * 0.95, 128);
constexpr float AG256  = fpowc(0.99 * 0.95, 256);
constexpr float AG512  = fpowc(0.99 * 0.95, 512);
constexpr float AG1024 = fpowc(0.99 * 0.95, 1024);
constexpr float AG2048 = fpowc(0.99 * 0.95, 2048);   // -> 0.0f (negligible, exact enough)
constexpr float G4     = fpowc(0.99, 4);
constexpr float G8     = fpowc(0.99, 8);
constexpr float G16    = fpowc(0.99, 16);
constexpr float G32    = fpowc(0.99, 32);
constexpr float G64    = fpowc(0.99, 64);
constexpr float G128   = fpowc(0.99, 128);
constexpr float G256   = fpowc(0.99, 256);
constexpr float G512   = fpowc(0.99, 512);
constexpr float G1024  = fpowc(0.99, 1024);
constexpr float G2048  = fpowc(0.99, 2048);          // 1.15e-9

// inclusive wave suffix scan, geometric lane-step weight w0 (6 shfls, no barriers)
__device__ __forceinline__ float wscan(float val, float w, int lane) {
#pragma unroll
    for (int s = 1; s < 64; s <<= 1) {
        float o = __shfl_down(val, s, 64);
        val += (lane + s < 64) ? w * o : 0.0f;
        w *= w;
    }
    return val;
}

// element i (compile-time under #pragma unroll / forceinline) of a float4[8] block
__device__ __forceinline__ float gx(const float4* a, int i) {
    const float4 f = a[i >> 2];
    const int k = i & 3;
    return k == 0 ? f.x : k == 1 ? f.y : k == 2 ? f.z : f.w;
}

// loss for one 4-elem block bb (3..0 within it), advancing the serial y/tt chains
__device__ __forceinline__ void lossblk(
    int bb, const float4& PP, const float4& QQ,
    const float4* r4, const float4* v4, float vlast,
    float& y, float& tt, float& acc)
{
    const float pp[4] = { PP.x, PP.y, PP.z, PP.w };
    const float qq[4] = { QQ.x, QQ.y, QQ.z, QQ.w };
#pragma unroll
    for (int k = 3; k >= 0; --k) {
        const int i = 4 * bb + k;
        const float vn = (i < MPT - 1) ? gx(v4, i + 1) : vlast;
        const float dd = gx(r4, i) - gx(v4, i) + GF * vn;
        y  = fmaf(AGLF, y, dd);             // advantage at elem i
        tt = fmaf(GF, tt, gx(r4, i));       // value target at elem i
        const float rt   = __fdividef(pp[k], qq[k]);
        const float cl   = fminf(fmaxf(rt, 1.0f - EPSF), 1.0f + EPSF);
        const float term = fminf(rt * y, cl * y);
        const float vd   = gx(v4, i) - tt;
        acc = fmaf(C1F * vd, vd, acc) - term - C2F * pp[k] * __logf(pp[k] + 1e-5f);
    }
}

__global__ __launch_bounds__(NT) void ppo_main(
    const float* __restrict__ probs,
    const float* __restrict__ probs_old,
    const float* __restrict__ rewards,
    const float* __restrict__ values,
    float* __restrict__ out)
{
    __shared__ __align__(16) float sx[16];   // {Hg[4], Hr[4], Wg[4], Wr[4]}
    __shared__ float sRed[NW];

    const int  j    = threadIdx.x;
    const int  lane = j & 63;
    const int  wid  = j >> 6;
    const int  c    = blockIdx.x;
    const long base = (long)c * CHUNK;
    const long g0   = base + (long)MPT * j;
    const bool has_halo = (c != NBLK - 1);

    // ---------------- loads: r/v (32/thread) + halo; p/q deferred ----------------
    float4 r4[8], v4[8];
#pragma unroll
    for (int b = 0; b < 8; ++b) {
        r4[b] = *reinterpret_cast<const float4*>(rewards + g0 + 4 * b);
        v4[b] = *reinterpret_cast<const float4*>(values  + g0 + 4 * b);
    }
    const float vlast = (g0 + MPT < T_TOTAL) ? values[g0 + MPT] : 0.0f;

    float4 hr4 = make_float4(0,0,0,0), hv4 = make_float4(0,0,0,0);
    float  hvn = 0.0f;
    if (has_halo) {
        const long hb = base + CHUNK + 4L * j;               // thread covers 4 halo elems
        hr4 = *reinterpret_cast<const float4*>(rewards + hb);
        hv4 = *reinterpret_cast<const float4*>(values  + hb);
        hvn = values[base + CHUNK + 256L * wid + 256];       // uniform per wave, in range
    }

    // ---------------- main: Horner over 32 elems, wave scan ----------------
    float Pg = 0.0f, Pr = 0.0f;
#pragma unroll
    for (int i = MPT - 1; i >= 0; --i) {
        const float vn = (i < MPT - 1) ? gx(v4, i + 1) : vlast;
        const float dd = gx(r4, i) - gx(v4, i) + GF * vn;
        Pg = fmaf(AGLF, Pg, dd);
        Pr = fmaf(GF,   Pr, gx(r4, i));
    }
    const float Ug = wscan(Pg, AG32, lane);
    const float Ur = wscan(Pr, G32,  lane);
    float sng = __shfl_down(Ug, 1, 64); sng = (lane < 63) ? sng : 0.0f;
    float snr = __shfl_down(Ur, 1, 64); snr = (lane < 63) ? snr : 0.0f;

    // ---------------- halo: per-thread 4-elem Horner, pre-weighted butterfly ----------
    float hg = 0.0f, hr = 0.0f;
    {
        float t = __shfl_down(hv4.x, 1, 64);
        const float vn3 = (lane < 63) ? t : hvn;
        const float d0 = hr4.x - hv4.x + GF * hv4.y;
        const float d1 = hr4.y - hv4.y + GF * hv4.z;
        const float d2 = hr4.z - hv4.z + GF * hv4.w;
        const float d3 = hr4.w - hv4.w + GF * vn3;
        float pwg = 1.f, pwr = 1.f;                          // a^(4*lane)
        if (lane & 1)  { pwg *= AG4;   pwr *= G4;   }
        if (lane & 2)  { pwg *= AG8;   pwr *= G8;   }
        if (lane & 4)  { pwg *= AG16;  pwr *= G16;  }
        if (lane & 8)  { pwg *= AG32;  pwr *= G32;  }
        if (lane & 16) { pwg *= AG64;  pwr *= G64;  }
        if (lane & 32) { pwg *= AG128; pwr *= G128; }
        hg = (d0 + AGLF * (d1 + AGLF * (d2 + AGLF * d3))) * pwg;
        hr = (hr4.x + GF * (hr4.y + GF * (hr4.z + GF * hr4.w))) * pwr;
#pragma unroll
        for (int t2 = 1; t2 < 64; t2 <<= 1) {
            hg += __shfl_xor(hg, t2, 64);
            hr += __shfl_xor(hr, t2, 64);
        }
    }
    if (lane == 0) {
        sx[wid]      = hg;   // halo strip partial (256 elems)
        sx[4 + wid]  = hr;
        sx[8 + wid]  = Ug;   // wave main total (2048 elems)
        sx[12 + wid] = Ur;
    }

    // ---------------- issue first p/q prefetches (b=7,6) before the barrier ----------
    float4 pA = *reinterpret_cast<const float4*>(probs     + g0 + 28);
    float4 qA = *reinterpret_cast<const float4*>(probs_old + g0 + 28);
    float4 pB = *reinterpret_cast<const float4*>(probs     + g0 + 24);
    float4 qB = *reinterpret_cast<const float4*>(probs_old + g0 + 24);

    __builtin_amdgcn_sched_barrier(0);
    asm volatile("s_waitcnt lgkmcnt(0)" ::: "memory");   // LDS writes visible; vmcnt untouched
    __builtin_amdgcn_s_barrier();
    __builtin_amdgcn_sched_barrier(0);

    // ---------------- carries ----------------
    const float4 Hgv = *reinterpret_cast<const float4*>(&sx[0]);
    const float4 Hrv = *reinterpret_cast<const float4*>(&sx[4]);
    const float4 Wgv = *reinterpret_cast<const float4*>(&sx[8]);
    const float4 Wrv = *reinterpret_cast<const float4*>(&sx[12]);

    // halo carry at chunk end (strips of 256)
    float Kg = Hgv.x + AG256 * (Hgv.y + AG256 * (Hgv.z + AG256 * Hgv.w));
    float Kr = Hrv.x + G256  * (Hrv.y + G256  * (Hrv.z + G256  * Hrv.w));
    // carry entering this wave's 2048-elem region (wid-uniform predicates)
    float Cg = Kg, Cr = Kr;
    if (3 > wid) { Cg = fmaf(AG2048, Cg, Wgv.w); Cr = fmaf(G2048, Cr, Wrv.w); }
    if (2 > wid) { Cg = fmaf(AG2048, Cg, Wgv.z); Cr = fmaf(G2048, Cr, Wrv.z); }
    if (1 > wid) { Cg = fmaf(AG2048, Cg, Wgv.y); Cr = fmaf(G2048, Cr, Wrv.y); }

    // per-lane carry weight (a^32)^(63-lane)
    const int k63 = 63 - lane;
    float wgl = 1.f, wrl = 1.f;
    if (k63 & 1)  { wgl *= AG32;   wrl *= G32;   }
    if (k63 & 2)  { wgl *= AG64;   wrl *= G64;   }
    if (k63 & 4)  { wgl *= AG128;  wrl *= G128;  }
    if (k63 & 8)  { wgl *= AG256;  wrl *= G256;  }
    if (k63 & 16) { wgl *= AG512;  wrl *= G512;  }
    if (k63 & 32) { wgl *= AG1024; wrl *= G1024; }

    float y  = fmaf(wgl, Cg, sng);   // advantage-scan value entering this lane's 32-run
    float tt = fmaf(wrl, Cr, snr);   // return-scan value entering this lane's 32-run

    // ---------------- fused reverse scan + loss, static ping-pong p/q prefetch -------
    float acc = 0.0f;
    lossblk(7, pA, qA, r4, v4, vlast, y, tt, acc);
    pA = *reinterpret_cast<const float4*>(probs     + g0 + 20);
    qA = *reinterpret_cast<const float4*>(probs_old + g0 + 20);
    lossblk(6, pB, qB, r4, v4, vlast, y, tt, acc);
    pB = *reinterpret_cast<const float4*>(probs     + g0 + 16);
    qB = *reinterpret_cast<const float4*>(probs_old + g0 + 16);
    lossblk(5, pA, qA, r4, v4, vlast, y, tt, acc);
    pA = *reinterpret_cast<const float4*>(probs     + g0 + 12);
    qA = *reinterpret_cast<const float4*>(probs_old + g0 + 12);
    lossblk(4, pB, qB, r4, v4, vlast, y, tt, acc);
    pB = *reinterpret_cast<const float4*>(probs     + g0 + 8);
    qB = *reinterpret_cast<const float4*>(probs_old + g0 + 8);
    lossblk(3, pA, qA, r4, v4, vlast, y, tt, acc);
    pA = *reinterpret_cast<const float4*>(probs     + g0 + 4);
    qA = *reinterpret_cast<const float4*>(probs_old + g0 + 4);
    lossblk(2, pB, qB, r4, v4, vlast, y, tt, acc);
    pB = *reinterpret_cast<const float4*>(probs     + g0);
    qB = *reinterpret_cast<const float4*>(probs_old + g0);
    lossblk(1, pA, qA, r4, v4, vlast, y, tt, acc);
    lossblk(0, pB, qB, r4, v4, vlast, y, tt, acc);

    // ---------------- reduce: wave butterfly -> 4 partials -> one atomic ----------
#pragma unroll
    for (int t = 32; t >= 1; t >>= 1) acc += __shfl_down(acc, t, 64);
    if (lane == 0) sRed[wid] = acc;
    __syncthreads();
    if (j == 0) atomicAdd(out, (sRed[0] + sRed[1]) + (sRed[2] + sRed[3]));
}

extern "C" void kernel_launch(void* const* d_in, const int* in_sizes, int n_in,
                              void* d_out, int out_size, void* d_ws, size_t ws_size,
                              hipStream_t stream) {
    const float* probs     = (const float*)d_in[0];
    const float* probs_old = (const float*)d_in[1];
    const float* rewards   = (const float*)d_in[2];
    const float* values    = (const float*)d_in[3];
    float* out = (float*)d_out;

    hipMemsetAsync(out, 0, sizeof(float), stream);   // d_out is poisoned 0xAA before every call
    ppo_main<<<NBLK, NT, 0, stream>>>(probs, probs_old, rewards, values, out);
}

// Round 7
// 152.467 us; speedup vs baseline: 1.3349x; 1.0424x over previous
//
#include <hip/hip_runtime.h>

// PPO loss, T = 2^23 fp32.
// out = -sum(min(ratio*adv, clip(ratio)*adv)) + C1*sum((v-ret)^2) - C2*sum(p*log(p+1e-5))
// adv: reverse scan gae = (gl)*gae + delta ; ret: reverse scan acc = g*acc + r.
//
// Round 7: fully INDEPENDENT WAVES (zero barriers, zero LDS) to break burst-lockstep:
// every round so far measured ~2.8 TB/s effective BW regardless of structure; the
// common factor was barrier-synced waves issuing one load burst then going silent.
// Each wave owns 2048 elems + its own geometric halo (returns W=768: gamma^768*tail
// ~ 1e-2/elem -> ~2e4 total error << 4.4e6 threshold; GAE W=256: (gl)^256 ~ 1.5e-7).
// Wave processes 4 tiles of 512 right-to-left, ping-pong register sets so the next
// tile's loads are in flight under the current tile's compute. Per-wave partial ->
// d_ws, tiny second kernel reduces 4096 partials.

#define T_TOTAL 8388608L
#define WCHUNK  2048
#define TILE    512
#define NWAVES  4096
#define NBLK    1024
#define NT      256
#define WR_HALO 768
#define WG_HALO 256

#define EPSF 0.2f
#define GF   0.99f
#define C1F  0.5f
#define C2F  0.01f
#define AGLF ((float)(0.99 * 0.95))

constexpr float fpowc(double a, int n) {
    double r = 1.0;
    for (int i = 0; i < n; ++i) r *= a;
    return (r < 1e-40) ? 0.0f : (float)r;
}
constexpr float AG4   = fpowc(0.99 * 0.95, 4);
constexpr float AG8   = fpowc(0.99 * 0.95, 8);
constexpr float AG16  = fpowc(0.99 * 0.95, 16);
constexpr float AG32  = fpowc(0.99 * 0.95, 32);
constexpr float AG64  = fpowc(0.99 * 0.95, 64);
constexpr float AG128 = fpowc(0.99 * 0.95, 128);
constexpr float AG256 = fpowc(0.99 * 0.95, 256);
constexpr float G8    = fpowc(0.99, 8);
constexpr float G16   = fpowc(0.99, 16);
constexpr float G32   = fpowc(0.99, 32);
constexpr float G64   = fpowc(0.99, 64);
constexpr float G128  = fpowc(0.99, 128);
constexpr float G256  = fpowc(0.99, 256);
constexpr float G12   = fpowc(0.99, 12);
constexpr float G24   = fpowc(0.99, 24);
constexpr float G48   = fpowc(0.99, 48);
constexpr float G96   = fpowc(0.99, 96);
constexpr float G192  = fpowc(0.99, 192);
constexpr float G384  = fpowc(0.99, 384);

__device__ __forceinline__ float4 ld4(const float* p) {
    return *reinterpret_cast<const float4*>(p);
}

// inclusive wave suffix scan, geometric lane-step weight w0 (6 shfls, no barriers)
__device__ __forceinline__ float wscan(float val, float w, int lane) {
#pragma unroll
    for (int s = 1; s < 64; s <<= 1) {
        float o = __shfl_down(val, s, 64);
        val += (lane + s < 64) ? w * o : 0.0f;
        w *= w;
    }
    return val;
}

struct TileRegs { float4 r0, r1, v0, v1, p0, p1, q0, q1; };

__device__ __forceinline__ void load_tile(TileRegs& X,
    const float* __restrict__ P, const float* __restrict__ Q,
    const float* __restrict__ R, const float* __restrict__ V,
    long tb, int lane)
{
    const long a = tb + 8L * lane;
    X.r0 = ld4(R + a); X.r1 = ld4(R + a + 4);
    X.v0 = ld4(V + a); X.v1 = ld4(V + a + 4);
    X.p0 = ld4(P + a); X.p1 = ld4(P + a + 4);
    X.q0 = ld4(Q + a); X.q1 = ld4(Q + a + 4);
}

// One 512-elem tile: wave scan + fused reverse-scan loss. Cg/Cr on entry are the
// scan values at elem tb+512 (inclusive); on exit, at elem tb.
__device__ __forceinline__ void proc_tile(const TileRegs& X, float vedge,
    float wgl, float wrl, int lane, float& Cg, float& Cr, float& acc)
{
    float t0 = __shfl_down(X.v0.x, 1, 64);
    const float vn7 = (lane < 63) ? t0 : vedge;                 // v[tb+8l+8]
    const float rr[8] = {X.r0.x,X.r0.y,X.r0.z,X.r0.w,X.r1.x,X.r1.y,X.r1.z,X.r1.w};
    const float vv[8] = {X.v0.x,X.v0.y,X.v0.z,X.v0.w,X.v1.x,X.v1.y,X.v1.z,X.v1.w};
    const float vx[8] = {X.v0.y,X.v0.z,X.v0.w,X.v1.x,X.v1.y,X.v1.z,X.v1.w,vn7};
    float d[8];
#pragma unroll
    for (int i = 0; i < 8; ++i) d[i] = rr[i] - vv[i] + GF * vx[i];

    float Pg = 0.0f, Pr = 0.0f;
#pragma unroll
    for (int i = 7; i >= 0; --i) {
        Pg = fmaf(AGLF, Pg, d[i]);
        Pr = fmaf(GF,   Pr, rr[i]);
    }
    const float Ug = wscan(Pg, AG8, lane);
    const float Ur = wscan(Pr, G8,  lane);
    float sng = __shfl_down(Ug, 1, 64); sng = (lane < 63) ? sng : 0.0f;
    float snr = __shfl_down(Ur, 1, 64); snr = (lane < 63) ? snr : 0.0f;

    float y  = fmaf(wgl, Cg, sng);    // scan value entering this lane's 8-run
    float tt = fmaf(wrl, Cr, snr);

    const float pp[8] = {X.p0.x,X.p0.y,X.p0.z,X.p0.w,X.p1.x,X.p1.y,X.p1.z,X.p1.w};
    const float qq[8] = {X.q0.x,X.q0.y,X.q0.z,X.q0.w,X.q1.x,X.q1.y,X.q1.z,X.q1.w};
#pragma unroll
    for (int i = 7; i >= 0; --i) {
        y  = fmaf(AGLF, y, d[i]);            // advantage at elem i
        tt = fmaf(GF, tt, rr[i]);            // value target at elem i
        const float rt   = __fdividef(pp[i], qq[i]);
        const float cl   = fminf(fmaxf(rt, 1.0f - EPSF), 1.0f + EPSF);
        const float term = fminf(rt * y, cl * y);
        const float vd   = vv[i] - tt;
        acc = fmaf(C1F * vd, vd, acc) - term - C2F * pp[i] * __logf(pp[i] + 1e-5f);
    }
    // carries for the tile to the left: lane 0's final y/tt = scan at elem tb
    Cg = __shfl(y,  0, 64);
    Cr = __shfl(tt, 0, 64);
}

__global__ __launch_bounds__(NT) void ppo_main(
    const float* __restrict__ probs,
    const float* __restrict__ probs_old,
    const float* __restrict__ rewards,
    const float* __restrict__ values,
    float* __restrict__ part)
{
    const int  j    = threadIdx.x;
    const int  lane = j & 63;
    const int  wid  = j >> 6;
    const int  gw   = blockIdx.x * 4 + wid;        // global wave id, owns 2048 elems
    const long wb   = (long)gw * WCHUNK;
    const bool has_halo = (gw != NWAVES - 1);

    // ---------- issue loads: T3 first, halo, T2 (T1/T0 issued inside the loop) ----------
    TileRegs A, B;
    load_tile(A, probs, probs_old, rewards, values, wb + 3L * TILE, lane);
    float4 h0, h1, h2, hgr, hgv;
    float  hve = 0.0f;
    if (has_halo) {
        const long he = wb + WCHUNK;
        h0  = ld4(rewards + he + 12L * lane);      // returns halo: 12 elems/lane, W=768
        h1  = ld4(rewards + he + 12L * lane + 4);
        h2  = ld4(rewards + he + 12L * lane + 8);
        hgr = ld4(rewards + he + 4L * lane);       // GAE halo: 4 elems/lane, W=256
        hgv = ld4(values  + he + 4L * lane);
        hve = values[he + 256];
    } else {
        h0 = h1 = h2 = hgr = hgv = make_float4(0.f, 0.f, 0.f, 0.f);
    }
    load_tile(B, probs, probs_old, rewards, values, wb + 2L * TILE, lane);
    const float vend = has_halo ? values[wb + WCHUNK] : 0.0f;   // v at chunk end
    const float ve2  = values[wb + 1536];                        // tile edges (in range always)
    const float ve1  = values[wb + 1024];
    const float ve0  = values[wb + 512];

    // ---------- per-lane constant weights (overlap load latency) ----------
    const int k63 = 63 - lane;
    float wgl = 1.f, wrl = 1.f;                    // (a^8)^(63-lane)
    if (k63 & 1)  { wgl *= AG8;   wrl *= G8;   }
    if (k63 & 2)  { wgl *= AG16;  wrl *= G16;  }
    if (k63 & 4)  { wgl *= AG32;  wrl *= G32;  }
    if (k63 & 8)  { wgl *= AG64;  wrl *= G64;  }
    if (k63 & 16) { wgl *= AG128; wrl *= G128; }
    if (k63 & 32) { wgl *= AG256; wrl *= G256; }
    float pg4 = 1.f, pr12 = 1.f;                   // (gl)^(4*lane), g^(12*lane)
    if (lane & 1)  { pg4 *= AG4;   pr12 *= G12;  }
    if (lane & 2)  { pg4 *= AG8;   pr12 *= G24;  }
    if (lane & 4)  { pg4 *= AG16;  pr12 *= G48;  }
    if (lane & 8)  { pg4 *= AG32;  pr12 *= G96;  }
    if (lane & 16) { pg4 *= AG64;  pr12 *= G192; }
    if (lane & 32) { pg4 *= AG128; pr12 *= G384; }

    // ---------- wave-local halo carries (butterfly; no LDS) ----------
    float Kg = 0.0f, Kr = 0.0f;
    if (has_halo) {
        float t = __shfl_down(hgv.x, 1, 64);
        const float vn3 = (lane < 63) ? t : hve;
        const float d0 = hgr.x - hgv.x + GF * hgv.y;
        const float d1 = hgr.y - hgv.y + GF * hgv.z;
        const float d2 = hgr.z - hgv.z + GF * hgv.w;
        const float d3 = hgr.w - hgv.w + GF * vn3;
        float kg = (d0 + AGLF * (d1 + AGLF * (d2 + AGLF * d3))) * pg4;
        float kr = h2.w;                            // Horner over 12 rewards
        kr = fmaf(GF, kr, h2.z); kr = fmaf(GF, kr, h2.y); kr = fmaf(GF, kr, h2.x);
        kr = fmaf(GF, kr, h1.w); kr = fmaf(GF, kr, h1.z); kr = fmaf(GF, kr, h1.y);
        kr = fmaf(GF, kr, h1.x); kr = fmaf(GF, kr, h0.w); kr = fmaf(GF, kr, h0.z);
        kr = fmaf(GF, kr, h0.y); kr = fmaf(GF, kr, h0.x);
        kr *= pr12;
#pragma unroll
        for (int s = 1; s < 64; s <<= 1) {
            kg += __shfl_xor(kg, s, 64);
            kr += __shfl_xor(kr, s, 64);
        }
        Kg = kg; Kr = kr;
    }

    // ---------- tiles right-to-left, ping-pong prefetch ----------
    float Cg = Kg, Cr = Kr, acc = 0.0f;
    proc_tile(A, vend, wgl, wrl, lane, Cg, Cr, acc);                       // T3
    load_tile(A, probs, probs_old, rewards, values, wb + 1L * TILE, lane); // T1 in flight
    proc_tile(B, ve2, wgl, wrl, lane, Cg, Cr, acc);                        // T2
    load_tile(B, probs, probs_old, rewards, values, wb, lane);             // T0 in flight
    proc_tile(A, ve1, wgl, wrl, lane, Cg, Cr, acc);                        // T1
    proc_tile(B, ve0, wgl, wrl, lane, Cg, Cr, acc);                        // T0

    // ---------- wave reduce -> per-wave partial ----------
#pragma unroll
    for (int s = 32; s >= 1; s >>= 1) acc += __shfl_down(acc, s, 64);
    if (lane == 0) part[gw] = acc;
}

__global__ __launch_bounds__(256) void ppo_reduce(
    const float* __restrict__ part, float* __restrict__ out)
{
    __shared__ float s[4];
    const int j = threadIdx.x, lane = j & 63, wid = j >> 6;
    const float4 a = ld4(part + 16 * j);
    const float4 b = ld4(part + 16 * j + 4);
    const float4 c = ld4(part + 16 * j + 8);
    const float4 d = ld4(part + 16 * j + 12);
    float x = ((a.x + a.y) + (a.z + a.w)) + ((b.x + b.y) + (b.z + b.w))
            + ((c.x + c.y) + (c.z + c.w)) + ((d.x + d.y) + (d.z + d.w));
#pragma unroll
    for (int s2 = 32; s2 >= 1; s2 >>= 1) x += __shfl_down(x, s2, 64);
    if (lane == 0) s[wid] = x;
    __syncthreads();
    if (j == 0) out[0] = (s[0] + s[1]) + (s[2] + s[3]);
}

extern "C" void kernel_launch(void* const* d_in, const int* in_sizes, int n_in,
                              void* d_out, int out_size, void* d_ws, size_t ws_size,
                              hipStream_t stream) {
    const float* probs     = (const float*)d_in[0];
    const float* probs_old = (const float*)d_in[1];
    const float* rewards   = (const float*)d_in[2];
    const float* values    = (const float*)d_in[3];
    float* part = (float*)d_ws;                 // NWAVES floats of scratch
    float* out  = (float*)d_out;

    ppo_main<<<NBLK, NT, 0, stream>>>(probs, probs_old, rewards, values, part);
    ppo_reduce<<<1, 256, 0, stream>>>(part, out);
}